// Round 4
// baseline (35381.778 us; speedup 1.0000x reference)
//
#include <hip/hip_runtime.h>

#define T_LEN 1024
#define B_N   64
#define D_N   256
#define Q_N   128
#define WCOLS 2816      // Wcat: 256 w | 256 pu | 256 pv | 1024 gi | 1024 gh
#define GROW  1792      // exchanged row: 768 (w|pu|pv) + 1024 (gi+gh summed)
#define NT    256

typedef __attribute__((ext_vector_type(8))) short short8;
typedef __attribute__((ext_vector_type(4))) float floatx4;

#define MFMA16(A, B, C) __builtin_amdgcn_mfma_f32_16x16x32_bf16((A), (B), (C), 0, 0, 0)

__device__ __forceinline__ float fsigmoid(float x) { return 1.f / (1.f + __expf(-x)); }
__device__ __forceinline__ float ftanh(float x) {
  float ax = fabsf(x);
  float e = __expf(-2.f * ax);
  float r = (1.f - e) / (1.f + e);
  return (x < 0.f) ? -r : r;
}

// ---- sc0/sc1 (point-of-coherence) access helpers: no fences needed ----------
__device__ __forceinline__ floatx4 ld4_sc(const float* a) {
  floatx4 r;
  asm volatile("global_load_dwordx4 %0, %1, off sc0 sc1" : "=v"(r) : "v"(a) : "memory");
  return r;
}
__device__ __forceinline__ float ld1_sc(const float* a) {
  float r;
  asm volatile("global_load_dword %0, %1, off sc0 sc1" : "=v"(r) : "v"(a) : "memory");
  return r;
}
__device__ __forceinline__ void st1_sc(float* a, float v) {
  asm volatile("global_store_dword %0, %1, off sc0 sc1" :: "v"(a), "v"(v) : "memory");
}
__device__ __forceinline__ void vm_drain() { asm volatile("s_waitcnt vmcnt(0)" ::: "memory"); }
#define TIE(x) asm volatile("" : "+v"(x))

// 3-term truncation split of A: x = h + m + l + eps, |eps| <~ 2^-24 |x|
struct Split3 { short8 h, m, l; };
__device__ __forceinline__ Split3 split8(const float* x) {
  union U { unsigned u[4]; short8 s; } H, M, L;
#pragma unroll
  for (int i = 0; i < 4; ++i) {
    float x0 = x[2 * i], x1 = x[2 * i + 1];
    unsigned h0 = __float_as_uint(x0) & 0xffff0000u;
    unsigned h1 = __float_as_uint(x1) & 0xffff0000u;
    float r0 = x0 - __uint_as_float(h0);
    float r1 = x1 - __uint_as_float(h1);
    unsigned m0 = __float_as_uint(r0) & 0xffff0000u;
    unsigned m1 = __float_as_uint(r1) & 0xffff0000u;
    float s0 = r0 - __uint_as_float(m0);
    float s1 = r1 - __uint_as_float(m1);
    H.u[i] = (h0 >> 16) | h1;
    M.u[i] = (m0 >> 16) | m1;
    L.u[i] = (__float_as_uint(s0) >> 16) | (__float_as_uint(s1) & 0xffff0000u);
  }
  Split3 r; r.h = H.s; r.m = M.s; r.l = L.s; return r;
}

// 5-product split MFMA: hh, hm, mh, mm, lh  (dropped hl ~2^-17 static weight-l)
__device__ __forceinline__ floatx4 mfma5(floatx4 acc, const Split3& A, short8 Bh, short8 Bm) {
  acc = MFMA16(A.l, Bh, acc);
  acc = MFMA16(A.m, Bm, acc);
  acc = MFMA16(A.m, Bh, acc);
  acc = MFMA16(A.h, Bm, acc);
  acc = MFMA16(A.h, Bh, acc);
  return acc;
}

// ---------------- prep: W -> 2-way bf16 split; vstate=v0; counters=0 ---------
__global__ void prep_kernel(const float* __restrict__ Wpu, const float* __restrict__ Wqu,
                            const float* __restrict__ Wpv, const float* __restrict__ Wih,
                            const float* __restrict__ Whh, const float* __restrict__ v0,
                            unsigned short* __restrict__ Wh, unsigned short* __restrict__ Wm,
                            float* __restrict__ vstate, unsigned* __restrict__ ctrs) {
  int idx = blockIdx.x * 256 + threadIdx.x;
  const int total = WCOLS * 256;                // 720896
  if (idx < total) {
    int n = idx >> 8, k = idx & 255;
    float w;
    if      (n < 256)  w = Wqu[k * 256 + n];            // w:  (v^T Wqu)_n
    else if (n < 512)  w = Wpu[k * 256 + (n - 256)];    // pu
    else if (n < 768)  w = Wpv[k * 256 + (n - 512)];    // pv
    else if (n < 1792) w = Wih[(n - 768) * 256 + k];    // gi_j = sum_k v[k] Wih[j][k]
    else               w = Whh[(n - 1792) * 256 + k];   // gh_j = sum_k ut[k] Whh[j][k]
    unsigned hb = __float_as_uint(w) & 0xffff0000u;
    float r1 = w - __uint_as_float(hb);
    Wh[idx] = (unsigned short)(hb >> 16);
    Wm[idx] = (unsigned short)((__float_as_uint(r1) & 0xffff0000u) >> 16);
  } else if (idx < total + B_N * 256) {
    int i = idx - total;
    vstate[i] = v0[i];
  } else if (idx < total + B_N * 256 + 2048) {
    ctrs[idx - total - B_N * 256] = 0u;
  }
}

// ---------------- prep_M: M_b = Q^T Q (256x256 per batch), qs_b = sum_j q_j --
__global__ void prep_M(const float* __restrict__ q, float* __restrict__ Mout,
                       float* __restrict__ qsout) {
  extern __shared__ float qb[];                 // 128 x 257 (pad)
  const int b = blockIdx.x, tid = threadIdx.x;
  for (int j = 0; j < Q_N; ++j)
    qb[j * 257 + tid] = q[((size_t)j * B_N + b) * D_N + tid];
  __syncthreads();
  float s = 0.f;
  for (int j = 0; j < Q_N; ++j) s += qb[j * 257 + tid];
  qsout[b * 256 + tid] = s;
  for (int pe = 0; pe < 16; ++pe) {
    const int e0 = pe * 16;
    float acc[16];
#pragma unroll
    for (int e = 0; e < 16; ++e) acc[e] = 0.f;
    for (int j = 0; j < Q_N; ++j) {
      float qd = qb[j * 257 + tid];
#pragma unroll
      for (int e = 0; e < 16; ++e) acc[e] += qb[j * 257 + e0 + e] * qd;
    }
#pragma unroll
    for (int e = 0; e < 16; ++e)
      Mout[(size_t)b * 65536 + (size_t)(e0 + e) * 256 + tid] = acc[e];
  }
}

// ---------------- group sync: one monotone counter per (group, kind) ---------
__device__ __forceinline__ void wait_ctr(unsigned* c, unsigned target) {
  if (threadIdx.x < 64) {
    while (__hip_atomic_load(c, __ATOMIC_RELAXED, __HIP_MEMORY_SCOPE_AGENT) < target)
      __builtin_amdgcn_s_sleep(8);
  }
  __syncthreads();
}
__device__ __forceinline__ void signal_ctr(unsigned* c) {
  vm_drain();                        // asm sc1 stores reach point of coherence
  __syncthreads();                   // all waves drained
  if (threadIdx.x == 0)
    __hip_atomic_fetch_add(c, 1u, __ATOMIC_RELAXED, __HIP_MEMORY_SCOPE_AGENT);
}

// ---------------- main: 64 WGs x 256 thr; 4 groups x 16 WGs; b = g*16+m ------
__launch_bounds__(NT, 1)
__global__ void pq_main(const float* __restrict__ p,
                        const float* __restrict__ bih, const float* __restrict__ bhh,
                        const unsigned short* __restrict__ Wh,
                        const unsigned short* __restrict__ Wm,
                        const float* __restrict__ Mmat, const float* __restrict__ qs,
                        float* G, float* vstate, unsigned* ctrs,
                        float* __restrict__ out) {
  __shared__ float warr[256];
  __shared__ float2 red2[256];
  __shared__ float scal[2];          // beta, 1/r

  const int tid  = threadIdx.x;
  const int g    = blockIdx.x >> 4;
  const int m    = blockIdx.x & 15;
  const int b    = g * 16 + m;
  const int lane = tid & 63;
  const int widx = tid >> 6;             // wave 0..3
  const int gw   = m * 4 + widx;         // group-wave 0..63
  const int n1   = gw * 12;              // tile1: 12 cols of [w|pu|pv]
  const int n2   = 768  + gw * 16;       // tile2: gi cols
  const int n3   = 1792 + gw * 16;       // tile3: gh cols (same gate j as tile2)
  const int row  = lane & 15;
  const int kb   = lane >> 4;

  unsigned* cntA = ctrs + g * 64;
  unsigned* cntB = ctrs + g * 64 + 32;

  const float bI = bih[tid]       + bhh[tid];
  const float bF = bih[256 + tid] + bhh[256 + tid];
  const float bG = bih[512 + tid] + bhh[512 + tid];
  const float bO = bih[768 + tid] + bhh[768 + tid];
  const float qsd = qs[b * 256 + tid];
  float vprev = vstate[b * 256 + tid];   // plain: fresh from prep's L2 lines

  // ---- register-resident B fragments: 3 tiles x 2 splits x 8 k-steps ----
  short8 Bh1[8], Bm1[8], Bhg[8], Bmg[8], Bh2[8], Bm2[8];
#pragma unroll
  for (int ks = 0; ks < 8; ++ks) {
    int ko = ks * 32 + kb * 8;
    int c1 = (n1 + row) * 256 + ko;      // may overshoot 767 by 4 cols: unused
    int c2 = (n2 + row) * 256 + ko;
    int c3 = (n3 + row) * 256 + ko;
    Bh1[ks] = *(const short8*)&Wh[c1];  Bm1[ks] = *(const short8*)&Wm[c1];
    Bhg[ks] = *(const short8*)&Wh[c2];  Bmg[ks] = *(const short8*)&Wm[c2];
    Bh2[ks] = *(const short8*)&Wh[c3];  Bm2[ks] = *(const short8*)&Wm[c3];
  }

  // ---- gh tile for t=0 from p[0] (plain cached loads) ----
  floatx4 acc2 = {0.f, 0.f, 0.f, 0.f};
  {
    const float* pb = p + ((size_t)0 * B_N + g * 16) * D_N;
#pragma unroll
    for (int ks = 0; ks < 8; ++ks) {
      float xa[8];
      const float* pr = pb + row * D_N + ks * 32 + kb * 8;
      *(float4*)&xa[0] = *(const float4*)pr;
      *(float4*)&xa[4] = *(const float4*)(pr + 4);
      Split3 A = split8(xa);
      acc2 = mfma5(acc2, A, Bh2[ks], Bm2[ks]);
    }
  }

  float hout = 0.f;
  const float* vb = vstate + (size_t)(g * 16) * 256;

  for (int t = 0; t < T_LEN; ++t) {
    // ---- wait all v_t stored (fabric-level), then read A-frags via sc1 ----
    wait_ctr(cntB, (unsigned)(16 * t));

    floatx4 acc1 = {0.f, 0.f, 0.f, 0.f}, accg = {0.f, 0.f, 0.f, 0.f};
#pragma unroll
    for (int half = 0; half < 2; ++half) {
      floatx4 va[4][2];
#pragma unroll
      for (int k4 = 0; k4 < 4; ++k4) {
        const float* vr = vb + row * 256 + (half * 4 + k4) * 32 + kb * 8;
        va[k4][0] = ld4_sc(vr);
        va[k4][1] = ld4_sc(vr + 4);
      }
      vm_drain();
#pragma unroll
      for (int k4 = 0; k4 < 4; ++k4) { TIE(va[k4][0]); TIE(va[k4][1]); }
#pragma unroll
      for (int k4 = 0; k4 < 4; ++k4) {
        int ks = half * 4 + k4;
        float xa[8];
        *(floatx4*)&xa[0] = va[k4][0];
        *(floatx4*)&xa[4] = va[k4][1];
        Split3 A = split8(xa);
        acc1 = mfma5(acc1, A, Bh1[ks], Bm1[ks]);
        accg = mfma5(accg, A, Bhg[ks], Bmg[ks]);
      }
    }

    // ---- scatter my G slice via sc1 dword stores (drained before signal) ----
    {
      int col = lane & 15, r0 = (lane >> 4) * 4;
#pragma unroll
      for (int r = 0; r < 4; ++r) {
        size_t brow = (size_t)(g * 16 + r0 + r) * GROW;
        if (col < 12) st1_sc(&G[brow + n1 + col], acc1[r]);
        st1_sc(&G[brow + 768 + gw * 16 + col], accg[r] + acc2[r]);  // gi+gh
      }
    }
    signal_ctr(cntA);

    // ---- next-step gh tile: off the critical path ----
    floatx4 acc2n = {0.f, 0.f, 0.f, 0.f};
    if (t + 1 < T_LEN) {
      const float* pb = p + ((size_t)(t + 1) * B_N + g * 16) * D_N;
#pragma unroll
      for (int ks = 0; ks < 8; ++ks) {
        float xa[8];
        const float* pr = pb + row * D_N + ks * 32 + kb * 8;
        *(float4*)&xa[0] = *(const float4*)pr;
        *(float4*)&xa[4] = *(const float4*)(pr + 4);
        Split3 A = split8(xa);
        acc2n = mfma5(acc2n, A, Bh2[ks], Bm2[ks]);
      }
    }

    // ---- phase 2: wait all G slices; fetch my row (coalesced sc1) ----
    wait_ctr(cntA, (unsigned)(16 * (t + 1)));
    const float* gr = G + (size_t)b * GROW;
    float w_ = ld1_sc(gr + tid);
    float pu = ld1_sc(gr + 256 + tid);
    float pv = ld1_sc(gr + 512 + tid);
    float g0 = ld1_sc(gr + 768 + tid);
    float g1 = ld1_sc(gr + 1024 + tid);
    float g2 = ld1_sc(gr + 1280 + tid);
    float g3 = ld1_sc(gr + 1536 + tid);
    vm_drain();
    TIE(w_); TIE(pu); TIE(pv); TIE(g0); TIE(g1); TIE(g2); TIE(g3);

    float utd = p[((size_t)t * B_N + b) * D_N + tid];
    warr[tid] = w_;
    red2[tid] = make_float2(pu * utd + pv * vprev, qsd * w_);
    __syncthreads();
    if (tid < 64) {
      float2 s = red2[tid];
      float2 s1 = red2[tid + 64], s2 = red2[tid + 128], s3 = red2[tid + 192];
      s.x += s1.x + s2.x + s3.x;  s.y += s1.y + s2.y + s3.y;
#pragma unroll
      for (int off = 1; off < 64; off <<= 1) {
        s.x += __shfl_xor(s.x, off);
        s.y += __shfl_xor(s.y, off);
      }
      if (tid == 0) {
        float beta = s.x;
        float r = s.y + 128.f * beta;      // r = qs.w + Q*beta
        scal[0] = beta;
        scal[1] = 1.f / r;
      }
    }
    __syncthreads();

    // ---- m = M_b * w  (M symmetric; coalesced row-stream, L2-cached) ----
    {
      const float* Mb = Mmat + (size_t)b * 65536;
      float md = 0.f;
#pragma unroll 16
      for (int e = 0; e < 256; ++e) md += Mb[(size_t)e * 256 + tid] * warr[e];

      float beta = scal[0], invr = scal[1];
      float cctx = (md + beta * qsd) * invr;
      float cn = fsigmoid(g1 + bF) * cctx + fsigmoid(g0 + bI) * ftanh(g2 + bG);
      hout = fsigmoid(g3 + bO) * ftanh(cn);
      st1_sc(&vstate[(size_t)b * 256 + tid], hout);
      vprev = hout;
    }
    signal_ctr(cntB);
    acc2 = acc2n;
  }

  out[b * 256 + tid] = hout;
}

extern "C" void kernel_launch(void* const* d_in, const int* in_sizes, int n_in,
                              void* d_out, int out_size, void* d_ws, size_t ws_size,
                              hipStream_t stream) {
  const float* p   = (const float*)d_in[0];
  const float* q   = (const float*)d_in[1];
  const float* v0  = (const float*)d_in[2];
  const float* Wpu = (const float*)d_in[3];
  const float* Wqu = (const float*)d_in[4];
  const float* Wpv = (const float*)d_in[5];
  const float* Wih = (const float*)d_in[6];
  const float* Whh = (const float*)d_in[7];
  const float* bih = (const float*)d_in[8];
  const float* bhh = (const float*)d_in[9];
  float* out = (float*)d_out;

  char* ws = (char*)d_ws;
  unsigned short* Wh = (unsigned short*)(ws + 0x000000);   // 1,441,792 B
  unsigned short* Wm = (unsigned short*)(ws + 0x160000);   // 1,441,792 B
  float*    G      = (float*)(ws + 0x2C0000);              //   458,752 B
  float*    vstate = (float*)(ws + 0x330000);              //    65,536 B
  unsigned* ctrs   = (unsigned*)(ws + 0x340000);           //     8,192 B
  float*    qs     = (float*)(ws + 0x350000);              //    65,536 B
  float*    Mmat   = (float*)(ws + 0x360000);              // 16,777,216 B
  if (ws_size < 0x1360000u) return;

  const int prep_items = WCOLS * 256 + B_N * 256 + 2048;   // 739,328
  prep_kernel<<<(prep_items + 255) / 256, 256, 0, stream>>>(
      Wpu, Wqu, Wpv, Wih, Whh, v0, Wh, Wm, vstate, ctrs);

  const size_t m_smem = 128 * 257 * sizeof(float);          // 131,584 B
  hipFuncSetAttribute(reinterpret_cast<const void*>(prep_M),
                      hipFuncAttributeMaxDynamicSharedMemorySize, (int)m_smem);
  prep_M<<<64, 256, m_smem, stream>>>(q, Mmat, qs);

  pq_main<<<64, NT, 0, stream>>>(p, bih, bhh, Wh, Wm, Mmat, qs,
                                 G, vstate, ctrs, out);
}

// Round 5
// 18702.631 us; speedup vs baseline: 1.8918x; 1.8918x over previous
//
#include <hip/hip_runtime.h>

#define T_LEN 1024
#define B_N   64
#define D_N   256
#define Q_N   128
#define WCOLS 2816      // Wcat: 256 w | 256 pu | 256 pv | 1024 gi | 1024 gh
#define GROW  1792      // exchanged row: 768 (w|pu|pv) + 1024 (gi+gh summed)
#define NT    256

typedef __attribute__((ext_vector_type(8))) short short8;
typedef __attribute__((ext_vector_type(4))) float floatx4;

#define MFMA16(A, B, C) __builtin_amdgcn_mfma_f32_16x16x32_bf16((A), (B), (C), 0, 0, 0)

__device__ __forceinline__ float fsigmoid(float x) { return 1.f / (1.f + __expf(-x)); }
__device__ __forceinline__ float ftanh(float x) {
  float ax = fabsf(x);
  float e = __expf(-2.f * ax);
  float r = (1.f - e) / (1.f + e);
  return (x < 0.f) ? -r : r;
}

// ---- sc0/sc1 (point-of-coherence) access helpers: no fences needed ----------
__device__ __forceinline__ floatx4 ld4_sc(const float* a) {
  floatx4 r;
  asm volatile("global_load_dwordx4 %0, %1, off sc0 sc1" : "=v"(r) : "v"(a) : "memory");
  return r;
}
__device__ __forceinline__ float ld1_sc(const float* a) {
  float r;
  asm volatile("global_load_dword %0, %1, off sc0 sc1" : "=v"(r) : "v"(a) : "memory");
  return r;
}
__device__ __forceinline__ void st1_sc(float* a, float v) {
  asm volatile("global_store_dword %0, %1, off sc0 sc1" :: "v"(a), "v"(v) : "memory");
}
__device__ __forceinline__ void vm_drain() { asm volatile("s_waitcnt vmcnt(0)" ::: "memory"); }
#define TIE(x) asm volatile("" : "+v"(x))

// 3-term truncation split of A: x = h + m + l + eps, |eps| <~ 2^-24 |x|
struct Split3 { short8 h, m, l; };
__device__ __forceinline__ Split3 split8(const float* x) {
  union U { unsigned u[4]; short8 s; } H, M, L;
#pragma unroll
  for (int i = 0; i < 4; ++i) {
    float x0 = x[2 * i], x1 = x[2 * i + 1];
    unsigned h0 = __float_as_uint(x0) & 0xffff0000u;
    unsigned h1 = __float_as_uint(x1) & 0xffff0000u;
    float r0 = x0 - __uint_as_float(h0);
    float r1 = x1 - __uint_as_float(h1);
    unsigned m0 = __float_as_uint(r0) & 0xffff0000u;
    unsigned m1 = __float_as_uint(r1) & 0xffff0000u;
    float s0 = r0 - __uint_as_float(m0);
    float s1 = r1 - __uint_as_float(m1);
    H.u[i] = (h0 >> 16) | h1;
    M.u[i] = (m0 >> 16) | m1;
    L.u[i] = (__float_as_uint(s0) >> 16) | (__float_as_uint(s1) & 0xffff0000u);
  }
  Split3 r; r.h = H.s; r.m = M.s; r.l = L.s; return r;
}

// 5-product split MFMA: hh, hm, mh, mm, lh  (dropped hl ~2^-17 static weight-l)
__device__ __forceinline__ floatx4 mfma5(floatx4 acc, const Split3& A, short8 Bh, short8 Bm) {
  acc = MFMA16(A.l, Bh, acc);
  acc = MFMA16(A.m, Bm, acc);
  acc = MFMA16(A.m, Bh, acc);
  acc = MFMA16(A.h, Bm, acc);
  acc = MFMA16(A.h, Bh, acc);
  return acc;
}

// ---------------- prep: W -> 2-way bf16 split; vstate=v0; flags=0 ------------
__global__ void prep_kernel(const float* __restrict__ Wpu, const float* __restrict__ Wqu,
                            const float* __restrict__ Wpv, const float* __restrict__ Wih,
                            const float* __restrict__ Whh, const float* __restrict__ v0,
                            unsigned short* __restrict__ Wh, unsigned short* __restrict__ Wm,
                            float* __restrict__ vstate, unsigned* __restrict__ flags) {
  int idx = blockIdx.x * 256 + threadIdx.x;
  const int total = WCOLS * 256;                // 720896
  if (idx < total) {
    int n = idx >> 8, k = idx & 255;
    float w;
    if      (n < 256)  w = Wqu[k * 256 + n];            // w:  (v^T Wqu)_n
    else if (n < 512)  w = Wpu[k * 256 + (n - 256)];    // pu
    else if (n < 768)  w = Wpv[k * 256 + (n - 512)];    // pv
    else if (n < 1792) w = Wih[(n - 768) * 256 + k];    // gi_j = sum_k v[k] Wih[j][k]
    else               w = Whh[(n - 1792) * 256 + k];   // gh_j = sum_k ut[k] Whh[j][k]
    unsigned hb = __float_as_uint(w) & 0xffff0000u;
    float r1 = w - __uint_as_float(hb);
    Wh[idx] = (unsigned short)(hb >> 16);
    Wm[idx] = (unsigned short)((__float_as_uint(r1) & 0xffff0000u) >> 16);
  } else if (idx < total + B_N * 256) {
    int i = idx - total;
    vstate[i] = v0[i];
  } else if (idx < total + B_N * 256 + 2048) {
    flags[idx - total - B_N * 256] = 0u;
  }
}

// ---------------- prep_M: M_b = Q^T Q (256x256 per batch), qs_b = sum_j q_j --
__global__ void prep_M(const float* __restrict__ q, float* __restrict__ Mout,
                       float* __restrict__ qsout) {
  extern __shared__ float qb[];                 // 128 x 257 (pad)
  const int b = blockIdx.x, tid = threadIdx.x;
  for (int j = 0; j < Q_N; ++j)
    qb[j * 257 + tid] = q[((size_t)j * B_N + b) * D_N + tid];
  __syncthreads();
  float s = 0.f;
  for (int j = 0; j < Q_N; ++j) s += qb[j * 257 + tid];
  qsout[b * 256 + tid] = s;
  for (int pe = 0; pe < 16; ++pe) {
    const int e0 = pe * 16;
    float acc[16];
#pragma unroll
    for (int e = 0; e < 16; ++e) acc[e] = 0.f;
    for (int j = 0; j < Q_N; ++j) {
      float qd = qb[j * 257 + tid];
#pragma unroll
      for (int e = 0; e < 16; ++e) acc[e] += qb[j * 257 + e0 + e] * qd;
    }
#pragma unroll
    for (int e = 0; e < 16; ++e)
      Mout[(size_t)b * 65536 + (size_t)(e0 + e) * 256 + tid] = acc[e];
  }
}

// ---------------- group sync: 16 PARALLEL flags per (group, kind) ------------
__device__ __forceinline__ void wait_flags(const unsigned* f, unsigned val) {
  if (threadIdx.x < 64) {
    const unsigned* fp = f + (threadIdx.x & 15);
    unsigned v = __hip_atomic_load(fp, __ATOMIC_RELAXED, __HIP_MEMORY_SCOPE_AGENT);
    while (__any((int)(v < val))) {
      __builtin_amdgcn_s_sleep(1);
      v = __hip_atomic_load(fp, __ATOMIC_RELAXED, __HIP_MEMORY_SCOPE_AGENT);
    }
  }
  __syncthreads();                   // no acquire fence: data read via sc0sc1
}
__device__ __forceinline__ void signal_flag(unsigned* f, unsigned val) {
  vm_drain();                        // my wave's sc1 stores reached coherence pt
  __syncthreads();                   // all waves drained
  if (threadIdx.x == 0)
    __hip_atomic_store(f, val, __ATOMIC_RELAXED, __HIP_MEMORY_SCOPE_AGENT);
}

// ---------------- main: 64 WGs x 256 thr; 4 groups x 16 WGs; b = g*16+m ------
__launch_bounds__(NT, 1)
__global__ void pq_main(const float* __restrict__ p,
                        const float* __restrict__ bih, const float* __restrict__ bhh,
                        const unsigned short* __restrict__ Wh,
                        const unsigned short* __restrict__ Wm,
                        const float* __restrict__ Mmat, const float* __restrict__ qs,
                        float* G, float* vstate, unsigned* flags,
                        float* __restrict__ out) {
  __shared__ float warr[256];
  __shared__ float2 red2[256];
  __shared__ float scal[2];          // beta, 1/r

  const int tid  = threadIdx.x;
  const int g    = blockIdx.x >> 4;
  const int m    = blockIdx.x & 15;
  const int b    = g * 16 + m;
  const int lane = tid & 63;
  const int widx = tid >> 6;             // wave 0..3
  const int gw   = m * 4 + widx;         // group-wave 0..63
  const int n1   = gw * 12;              // tile1: 12 cols of [w|pu|pv]
  const int n2   = 768  + gw * 16;       // tile2: gi cols
  const int n3   = 1792 + gw * 16;       // tile3: gh cols (same gate j as tile2)
  const int row  = lane & 15;
  const int kb   = lane >> 4;

  unsigned* flagsA = flags + g * 64;       // 16 dwords (1 line)
  unsigned* flagsB = flags + g * 64 + 32;  // 16 dwords (next line)

  const float bI = bih[tid]       + bhh[tid];
  const float bF = bih[256 + tid] + bhh[256 + tid];
  const float bG = bih[512 + tid] + bhh[512 + tid];
  const float bO = bih[768 + tid] + bhh[768 + tid];
  const float qsd = qs[b * 256 + tid];
  float vprev = vstate[b * 256 + tid];   // plain: fresh via kernel-boundary flush

  // ---- register-resident B fragments: 3 tiles x 2 splits x 8 k-steps ----
  short8 Bh1[8], Bm1[8], Bhg[8], Bmg[8], Bh2[8], Bm2[8];
#pragma unroll
  for (int ks = 0; ks < 8; ++ks) {
    int ko = ks * 32 + kb * 8;
    int c1 = (n1 + row) * 256 + ko;      // may overshoot 767 by 4 cols: unused
    int c2 = (n2 + row) * 256 + ko;
    int c3 = (n3 + row) * 256 + ko;
    Bh1[ks] = *(const short8*)&Wh[c1];  Bm1[ks] = *(const short8*)&Wm[c1];
    Bhg[ks] = *(const short8*)&Wh[c2];  Bmg[ks] = *(const short8*)&Wm[c2];
    Bh2[ks] = *(const short8*)&Wh[c3];  Bm2[ks] = *(const short8*)&Wm[c3];
  }

  // ---- gh tile for t=0 from p[0] (plain cached loads) ----
  floatx4 acc2 = {0.f, 0.f, 0.f, 0.f};
  {
    const float* pb = p + ((size_t)0 * B_N + g * 16) * D_N;
#pragma unroll
    for (int ks = 0; ks < 8; ++ks) {
      float xa[8];
      const float* pr = pb + row * D_N + ks * 32 + kb * 8;
      *(float4*)&xa[0] = *(const float4*)pr;
      *(float4*)&xa[4] = *(const float4*)(pr + 4);
      Split3 A = split8(xa);
      acc2 = mfma5(acc2, A, Bh2[ks], Bm2[ks]);
    }
  }

  float hout = 0.f;
  const float* vb = vstate + (size_t)(g * 16) * 256;

  for (int t = 0; t < T_LEN; ++t) {
    // ---- wait all v_t stored; issue ALL 16 v-frag loads, ONE drain ----
    wait_flags(flagsB, (unsigned)t);

    floatx4 va[8][2];
#pragma unroll
    for (int ks = 0; ks < 8; ++ks) {
      const float* vr = vb + row * 256 + ks * 32 + kb * 8;
      va[ks][0] = ld4_sc(vr);
      va[ks][1] = ld4_sc(vr + 4);
    }
    vm_drain();
#pragma unroll
    for (int ks = 0; ks < 8; ++ks) { TIE(va[ks][0]); TIE(va[ks][1]); }

    floatx4 acc1 = {0.f, 0.f, 0.f, 0.f}, accg = {0.f, 0.f, 0.f, 0.f};
#pragma unroll
    for (int ks = 0; ks < 8; ++ks) {
      float xa[8];
      *(floatx4*)&xa[0] = va[ks][0];
      *(floatx4*)&xa[4] = va[ks][1];
      Split3 A = split8(xa);
      acc1 = mfma5(acc1, A, Bh1[ks], Bm1[ks]);
      accg = mfma5(accg, A, Bhg[ks], Bmg[ks]);
    }

    // ---- scatter my G slice via sc1 dword stores (drained before signal) ----
    {
      int col = lane & 15, r0 = (lane >> 4) * 4;
#pragma unroll
      for (int r = 0; r < 4; ++r) {
        size_t brow = (size_t)(g * 16 + r0 + r) * GROW;
        if (col < 12) st1_sc(&G[brow + n1 + col], acc1[r]);
        st1_sc(&G[brow + 768 + gw * 16 + col], accg[r] + acc2[r]);  // gi+gh
      }
    }
    signal_flag(&flagsA[m], (unsigned)(t + 1));

    // ---- next-step gh tile: off the critical path ----
    floatx4 acc2n = {0.f, 0.f, 0.f, 0.f};
    if (t + 1 < T_LEN) {
      const float* pb = p + ((size_t)(t + 1) * B_N + g * 16) * D_N;
#pragma unroll
      for (int ks = 0; ks < 8; ++ks) {
        float xa[8];
        const float* pr = pb + row * D_N + ks * 32 + kb * 8;
        *(float4*)&xa[0] = *(const float4*)pr;
        *(float4*)&xa[4] = *(const float4*)(pr + 4);
        Split3 A = split8(xa);
        acc2n = mfma5(acc2n, A, Bh2[ks], Bm2[ks]);
      }
    }

    // ---- phase 2: wait all G slices; fetch my row (coalesced sc1) ----
    wait_flags(flagsA, (unsigned)(t + 1));
    const float* gr = G + (size_t)b * GROW;
    float utd = p[((size_t)t * B_N + b) * D_N + tid];   // L2-hot (acc2 touched it)
    float w_ = ld1_sc(gr + tid);
    float pu = ld1_sc(gr + 256 + tid);
    float pv = ld1_sc(gr + 512 + tid);
    float g0 = ld1_sc(gr + 768 + tid);
    float g1 = ld1_sc(gr + 1024 + tid);
    float g2 = ld1_sc(gr + 1280 + tid);
    float g3 = ld1_sc(gr + 1536 + tid);
    vm_drain();
    TIE(w_); TIE(pu); TIE(pv); TIE(g0); TIE(g1); TIE(g2); TIE(g3);

    warr[tid] = w_;
    red2[tid] = make_float2(pu * utd + pv * vprev, qsd * w_);
    __syncthreads();
    if (tid < 64) {
      float2 s = red2[tid];
      float2 s1 = red2[tid + 64], s2 = red2[tid + 128], s3 = red2[tid + 192];
      s.x += s1.x + s2.x + s3.x;  s.y += s1.y + s2.y + s3.y;
#pragma unroll
      for (int off = 1; off < 64; off <<= 1) {
        s.x += __shfl_xor(s.x, off);
        s.y += __shfl_xor(s.y, off);
      }
      if (tid == 0) {
        float beta = s.x;
        float r = s.y + 128.f * beta;      // r = qs.w + Q*beta
        scal[0] = beta;
        scal[1] = 1.f / r;
      }
    }
    __syncthreads();

    // ---- md = (M_b w)[tid]: 4 independent chains, coalesced L2-hot stream ----
    {
      const float* Mb = Mmat + (size_t)b * 65536;
      float md0 = 0.f, md1 = 0.f, md2 = 0.f, md3 = 0.f;
#pragma unroll 8
      for (int e = 0; e < 256; e += 4) {
        md0 += Mb[(size_t)(e + 0) * 256 + tid] * warr[e + 0];
        md1 += Mb[(size_t)(e + 1) * 256 + tid] * warr[e + 1];
        md2 += Mb[(size_t)(e + 2) * 256 + tid] * warr[e + 2];
        md3 += Mb[(size_t)(e + 3) * 256 + tid] * warr[e + 3];
      }
      float md = (md0 + md1) + (md2 + md3);

      float beta = scal[0], invr = scal[1];
      float cctx = (md + beta * qsd) * invr;
      float cn = fsigmoid(g1 + bF) * cctx + fsigmoid(g0 + bI) * ftanh(g2 + bG);
      hout = fsigmoid(g3 + bO) * ftanh(cn);
      st1_sc(&vstate[(size_t)b * 256 + tid], hout);
      vprev = hout;
    }
    signal_flag(&flagsB[m], (unsigned)(t + 1));
    acc2 = acc2n;
  }

  out[b * 256 + tid] = hout;
}

extern "C" void kernel_launch(void* const* d_in, const int* in_sizes, int n_in,
                              void* d_out, int out_size, void* d_ws, size_t ws_size,
                              hipStream_t stream) {
  const float* p   = (const float*)d_in[0];
  const float* q   = (const float*)d_in[1];
  const float* v0  = (const float*)d_in[2];
  const float* Wpu = (const float*)d_in[3];
  const float* Wqu = (const float*)d_in[4];
  const float* Wpv = (const float*)d_in[5];
  const float* Wih = (const float*)d_in[6];
  const float* Whh = (const float*)d_in[7];
  const float* bih = (const float*)d_in[8];
  const float* bhh = (const float*)d_in[9];
  float* out = (float*)d_out;

  char* ws = (char*)d_ws;
  unsigned short* Wh = (unsigned short*)(ws + 0x000000);   // 1,441,792 B
  unsigned short* Wm = (unsigned short*)(ws + 0x160000);   // 1,441,792 B
  float*    G      = (float*)(ws + 0x2C0000);              //   458,752 B
  float*    vstate = (float*)(ws + 0x330000);              //    65,536 B
  unsigned* flags  = (unsigned*)(ws + 0x340000);           //     8,192 B
  float*    qs     = (float*)(ws + 0x350000);              //    65,536 B
  float*    Mmat   = (float*)(ws + 0x360000);              // 16,777,216 B
  if (ws_size < 0x1360000u) return;

  const int prep_items = WCOLS * 256 + B_N * 256 + 2048;   // 739,328
  prep_kernel<<<(prep_items + 255) / 256, 256, 0, stream>>>(
      Wpu, Wqu, Wpv, Wih, Whh, v0, Wh, Wm, vstate, flags);

  const size_t m_smem = 128 * 257 * sizeof(float);          // 131,584 B
  hipFuncSetAttribute(reinterpret_cast<const void*>(prep_M),
                      hipFuncAttributeMaxDynamicSharedMemorySize, (int)m_smem);
  prep_M<<<64, 256, m_smem, stream>>>(q, Mmat, qs);

  pq_main<<<64, NT, 0, stream>>>(p, bih, bhh, Wh, Wm, Mmat, qs,
                                 G, vstate, flags, out);
}